// Round 17
// baseline (818.283 us; speedup 1.0000x reference)
//
#include <hip/hip_runtime.h>
#include <hip/hip_bf16.h>

#define B_ 64
#define T_ 256
#define H_ 1024
#define NB_ 256  // 4 groups x 64 col-blocks
#define NKK_ 40

typedef __attribute__((ext_vector_type(8))) short short8;
typedef __attribute__((ext_vector_type(4))) float float4_;
typedef unsigned long long u64;

static __device__ __forceinline__ ushort f2bf(float v) {
  __hip_bfloat16 b = __float2bfloat16(v);
  return *reinterpret_cast<ushort*>(&b);
}
static __device__ __forceinline__ float bf2f(ushort u) {
  unsigned int x = ((unsigned int)u) << 16;
  return __builtin_bit_cast(float, x);
}
static __device__ __forceinline__ float sigm(float v) { return 1.0f / (1.0f + __expf(-v)); }
static __device__ __forceinline__ float tanh_fast(float v) {
  float e = __expf(2.0f * v);
  return 1.0f - 2.0f / (e + 1.0f);
}
// sentinel = 0xFFFF (bf16 -NaN). |h| < 1 -> data bf16 never sets bit14.
static __device__ __forceinline__ bool anyS(u64 q) {
  return (q & 0x4000400040004000ull) != 0ull;
}
static __device__ __forceinline__ float pick4(int r, float v0, float v1, float v2, float v3) {
  float x = (r == 1) ? v1 : v0;
  float y = (r == 3) ? v3 : v2;
  return (r & 2) ? y : x;
}

// Xall[t][b][j] bf16: j even = x[b][j/2][t], j odd = y[b][j/2][t-1] (0 at t=0)
__global__ __launch_bounds__(256) void build_X(const float* __restrict__ x,
                                               const float* __restrict__ y,
                                               ushort* __restrict__ Xall) {
  __shared__ float xl[128][33];
  __shared__ float yl[128][33];
  int b = blockIdx.x >> 3;
  int t0 = (blockIdx.x & 7) * 32;
  int tid = threadIdx.x;
  for (int it = 0; it < 16; ++it) {
    int idx = it * 256 + tid;
    int s = idx >> 5, tt = idx & 31;
    xl[s][tt] = x[((size_t)b * 128 + s) * T_ + t0 + tt];
    int ty = t0 + tt - 1;
    yl[s][tt] = (ty >= 0) ? y[((size_t)b * 128 + s) * T_ + ty] : 0.0f;
  }
  __syncthreads();
  for (int tt = 0; tt < 32; ++tt) {
    float v = (tid & 1) ? yl[tid >> 1][tt] : xl[tid >> 1][tt];
    Xall[((size_t)(t0 + tt) * B_ + b) * 256 + tid] = f2bf(v);
  }
}

// Round-2-verified B layout at nb granularity (nb = 4-col block, 0..255):
// Bp[(nb*40+kk)*64 + l][8]: lane l supplies B[k=32kk+8*(l>>4)+j][localcol=l&15]
// localcol q -> gate gt=q>>2, hcol m=q&3; col = nb*4+m of gate gt's W
__global__ __launch_bounds__(256) void prep_weights(const float* __restrict__ Wf,
                                                    const float* __restrict__ Wi,
                                                    const float* __restrict__ Wu,
                                                    const float* __restrict__ Wo,
                                                    ushort* __restrict__ Bp) {
  int flat = blockIdx.x * 256 + threadIdx.x;
  int l = flat & 63;
  int g2 = flat >> 6;
  int kk = g2 % NKK_;
  int nb = g2 / NKK_;
  int q = l & 15, kg = l >> 4;
  int gt = q >> 2, m = q & 3;
  const float* W = (gt == 0) ? Wf : (gt == 1) ? Wi : (gt == 2) ? Wu : Wo;
  int col = nb * 4 + m;
  ushort tmp[8];
#pragma unroll
  for (int j = 0; j < 8; ++j) {
    int k = kk * 32 + kg * 8 + j;
    tmp[j] = f2bf(W[(size_t)k * H_ + col]);
  }
  *(short8*)(Bp + (size_t)flat * 8) = *(short8*)tmp;
}

// Persistent LSTM, 4 groups x 64 col-blocks, 256-thread blocks (4 waves).
// Wave owns 4 h-cols x 4 gates with FULL K (40 frags) -> no cross-wave gate
// reduce: epilogue is 16 in-wave shuffles, publish issues right after the
// wave's MFMA chain. ONE barrier/step (post-stage); stg double-buffered by
// t-parity. Sentinel protocol identical to round 16.
template <bool FRESH>
__global__ __launch_bounds__(256) void lstm_persist(
    const ushort* __restrict__ Xall, const ushort* __restrict__ Bp,
    const float* __restrict__ bfp, const float* __restrict__ bip,
    const float* __restrict__ bup, const float* __restrict__ bop,
    ushort* __restrict__ Hh, float* __restrict__ out,
    unsigned int* __restrict__ flags) {
  __shared__ ushort stg[2][16][1024];    // 64 KB, XOR-swizzled rows
  __shared__ ushort hbuf[4][16][4][17];  // 8.7 KB out-burst [wv][row][m][16]
  const int tid = threadIdx.x;
  const int wv = tid >> 6, l = tid & 63;
  const int ar = l & 15, kg = l >> 4;
  const int g = blockIdx.x & 3, cbl = blockIdx.x >> 2;
  const int nb4 = cbl * 4 + wv;  // this wave's 4-col block (round-2 layout)

  short8 bfrag[NKK_];
  {
    const ushort* bp0 = Bp + (((size_t)nb4 * NKK_) * 64 + l) * 8;
#pragma unroll
    for (int u = 0; u < NKK_; ++u) bfrag[u] = *(const short8*)(bp0 + (size_t)u * 512);
  }
#pragma unroll
  for (int u = 0; u < NKK_; ++u) asm volatile("" : "+v"(bfrag[u]));

  // output role: lane (hi = l>>4, q = l&15) finalizes row hi*4 + (q>>2), col q&3
  const int rho = (l >> 2) & 3, m = l & 3, hi = l >> 4;
  const int row_o = hi * 4 + rho;
  const int hcol = cbl * 16 + wv * 4 + m;
  const float biasF = bfp[hcol], biasI = bip[hcol];
  const float biasU = bup[hcol], biasO = bop[hcol];
  float creg = 0.0f;
  // stage role: thread (srow = tid>>4, sc = tid&15) stages 128 B of row srow
  const int srow = tid >> 4, sc = tid & 15;

  for (int t = 0; t < T_; ++t) {
    const int par = t & 1;
    // ---- x-part: 8 MFMAs (kk 0..7), 4 interleaved accumulators ----
    const ushort* xrow = Xall + ((size_t)t * B_ + 16 * g + ar) * 256 + kg * 8;
    float4_ a0 = {0, 0, 0, 0}, a1 = {0, 0, 0, 0}, a2 = {0, 0, 0, 0}, a3 = {0, 0, 0, 0};
#pragma unroll
    for (int u = 0; u < 8; ++u) {
      short8 av = *(const short8*)(xrow + u * 32);
      if ((u & 3) == 0) a0 = __builtin_amdgcn_mfma_f32_16x16x32_bf16(av, bfrag[u], a0, 0, 0, 0);
      else if ((u & 3) == 1) a1 = __builtin_amdgcn_mfma_f32_16x16x32_bf16(av, bfrag[u], a1, 0, 0, 0);
      else if ((u & 3) == 2) a2 = __builtin_amdgcn_mfma_f32_16x16x32_bf16(av, bfrag[u], a2, 0, 0, 0);
      else a3 = __builtin_amdgcn_mfma_f32_16x16x32_bf16(av, bfrag[u], a3, 0, 0, 0);
    }
    if (t > 0) {
      if (!FRESH) {
        if (tid < 64) {
          unsigned int tgt = (unsigned int)t;
          while (true) {
            unsigned int f0 = __hip_atomic_load(&flags[g * 64 + l], __ATOMIC_RELAXED,
                                                __HIP_MEMORY_SCOPE_AGENT);
            if (__all(f0 >= tgt)) break;
            __builtin_amdgcn_s_sleep(1);
          }
          asm volatile("" ::: "memory");
        }
        __syncthreads();
      }
      // ---- stage 128 B of row srow: plain attempt + sc1 retries ----
      {
        const ushort* slotp = Hh + ((size_t)(FRESH ? t : par) * 4 + g) * 16384;
        const u64* pr = (const u64*)(slotp + (size_t)srow * 1024);
        u64 q[16];
        if (FRESH) {
#pragma unroll
          for (int i = 0; i < 8; ++i) {
            q[2 * i] = pr[sc * 2 + i * 32];
            q[2 * i + 1] = pr[sc * 2 + 1 + i * 32];
          }
          u64 acc_or = 0;
#pragma unroll
          for (int i = 0; i < 16; ++i) acc_or |= q[i];
          while (anyS(acc_or)) {
            __builtin_amdgcn_s_sleep(1);
#pragma unroll
            for (int i = 0; i < 8; ++i) {
              q[2 * i] = __hip_atomic_load(pr + sc * 2 + i * 32, __ATOMIC_RELAXED,
                                           __HIP_MEMORY_SCOPE_AGENT);
              q[2 * i + 1] = __hip_atomic_load(pr + sc * 2 + 1 + i * 32, __ATOMIC_RELAXED,
                                               __HIP_MEMORY_SCOPE_AGENT);
            }
            acc_or = 0;
#pragma unroll
            for (int i = 0; i < 16; ++i) acc_or |= q[i];
          }
        } else {
#pragma unroll
          for (int i = 0; i < 8; ++i) {
            q[2 * i] = __hip_atomic_load(pr + sc * 2 + i * 32, __ATOMIC_RELAXED,
                                         __HIP_MEMORY_SCOPE_AGENT);
            q[2 * i + 1] = __hip_atomic_load(pr + sc * 2 + 1 + i * 32, __ATOMIC_RELAXED,
                                             __HIP_MEMORY_SCOPE_AGENT);
          }
        }
        // LDS write: 16 B units, lane-stride 16 B (2-way, free) + row-XOR
#pragma unroll
        for (int i = 0; i < 8; ++i) {
          union { u64 qq[2]; short8 s; } cv;
          cv.qq[0] = q[2 * i]; cv.qq[1] = q[2 * i + 1];
          *(short8*)&stg[par][srow][(sc * 8 + i * 128) ^ ((srow & 7) << 3)] = cv.s;
        }
      }
      __syncthreads();  // the ONE barrier per step
      // ---- h-part: 32 MFMAs from swizzled LDS ----
#pragma unroll
      for (int u = 8; u < NKK_; ++u) {
        short8 av = *(const short8*)&stg[par][ar][((u - 8) * 32 + kg * 8) ^ ((ar & 7) << 3)];
        if ((u & 3) == 0) a0 = __builtin_amdgcn_mfma_f32_16x16x32_bf16(av, bfrag[u], a0, 0, 0, 0);
        else if ((u & 3) == 1) a1 = __builtin_amdgcn_mfma_f32_16x16x32_bf16(av, bfrag[u], a1, 0, 0, 0);
        else if ((u & 3) == 2) a2 = __builtin_amdgcn_mfma_f32_16x16x32_bf16(av, bfrag[u], a2, 0, 0, 0);
        else a3 = __builtin_amdgcn_mfma_f32_16x16x32_bf16(av, bfrag[u], a3, 0, 0, 0);
      }
    }
    float4_ accv = (a0 + a1) + (a2 + a3);
    // ---- in-wave gate gather: 16 shuffles, all reg indices static ----
    {
      const int sb = (l & 48) | (l & 3);
      float S00 = __shfl(accv[0], sb),      S01 = __shfl(accv[1], sb);
      float S02 = __shfl(accv[2], sb),      S03 = __shfl(accv[3], sb);
      float S10 = __shfl(accv[0], sb + 4),  S11 = __shfl(accv[1], sb + 4);
      float S12 = __shfl(accv[2], sb + 4),  S13 = __shfl(accv[3], sb + 4);
      float S20 = __shfl(accv[0], sb + 8),  S21 = __shfl(accv[1], sb + 8);
      float S22 = __shfl(accv[2], sb + 8),  S23 = __shfl(accv[3], sb + 8);
      float S30 = __shfl(accv[0], sb + 12), S31 = __shfl(accv[1], sb + 12);
      float S32 = __shfl(accv[2], sb + 12), S33 = __shfl(accv[3], sb + 12);
      float F = pick4(rho, S00, S01, S02, S03) + biasF;
      float I = pick4(rho, S10, S11, S12, S13) + biasI;
      float U = pick4(rho, S20, S21, S22, S23) + biasU;
      float O = pick4(rho, S30, S31, S32, S33) + biasO;
      creg = fmaf(creg, sigm(F), sigm(I) * tanh_fast(U));
      float h = sigm(O) * tanh_fast(creg);
      ushort hv = f2bf(h);
      // publish: pack 4 cols via in-wave shuffles; l%4==0 stores 8 B sc1
      unsigned int hw = hv;
      unsigned int h1 = __shfl_down(hw, 1);
      unsigned int h2 = __shfl_down(hw, 2);
      unsigned int h3 = __shfl_down(hw, 3);
      if ((l & 3) == 0) {
        u64 qv = (u64)hw | ((u64)h1 << 16) | ((u64)h2 << 32) | ((u64)h3 << 48);
        u64* dst = (u64*)(Hh +
            ((size_t)(FRESH ? (t + 1) : ((t + 1) & 1)) * 4 + g) * 16384 +
            (size_t)row_o * 1024 + cbl * 16 + wv * 4);
        __hip_atomic_store(dst, qv, __ATOMIC_RELAXED, __HIP_MEMORY_SCOPE_AGENT);
      }
      hbuf[wv][row_o][m][t & 15] = hv;
      if ((t & 15) == 15) {  // 64 B line-exact burst per thread
        float* orow = out + ((size_t)(16 * g + row_o) * H_ + hcol) * T_ + (t - 15);
#pragma unroll
        for (int tt = 0; tt < 16; tt += 4) {
          float4 v = {bf2f(hbuf[wv][row_o][m][tt]), bf2f(hbuf[wv][row_o][m][tt + 1]),
                      bf2f(hbuf[wv][row_o][m][tt + 2]), bf2f(hbuf[wv][row_o][m][tt + 3])};
          *(float4*)(orow + tt) = v;
        }
      }
    }
    if (!FRESH) {
      asm volatile("s_waitcnt vmcnt(0)" ::: "memory");
      __syncthreads();
      if (tid == 0)
        __hip_atomic_store(&flags[g * 64 + cbl], (unsigned int)(t + 1), __ATOMIC_RELAXED,
                           __HIP_MEMORY_SCOPE_AGENT);
    }
  }
  // ---- final c ----
  out[(size_t)B_ * H_ * T_ + (size_t)(16 * g + row_o) * H_ + hcol] = creg;
}

extern "C" void kernel_launch(void* const* d_in, const int* in_sizes, int n_in,
                              void* d_out, int out_size, void* d_ws, size_t ws_size,
                              hipStream_t stream) {
  const float* x  = (const float*)d_in[0];
  const float* y  = (const float*)d_in[2];
  const float* Wf = (const float*)d_in[3];  const float* bf = (const float*)d_in[4];
  const float* Wi = (const float*)d_in[5];  const float* bi = (const float*)d_in[6];
  const float* Wu = (const float*)d_in[7];  const float* bu = (const float*)d_in[8];
  const float* Wo = (const float*)d_in[9];  const float* bo = (const float*)d_in[10];
  float* out = (float*)d_out;

  char* p = (char*)d_ws;
  ushort* Bp = (ushort*)p;        p += (size_t)256 * NKK_ * 64 * 8 * 2;   // 10.49 MB
  ushort* Xall = (ushort*)p;      p += (size_t)T_ * B_ * 256 * 2;         // 8.39 MB
  unsigned int* flags = (unsigned int*)p; p += 4096;
  ushort* Hh = (ushort*)p;        // FRESH: (T+1) x 4 x 32 KB = 33.6 MB
  size_t head = (size_t)(p - (char*)d_ws);
  bool fresh = ws_size >= head + (size_t)(T_ + 1) * 4 * 16384 * 2;

  prep_weights<<<(256 * NKK_ * 64) / 256, 256, 0, stream>>>(Wf, Wi, Wu, Wo, Bp);
  build_X<<<B_ * 8, 256, 0, stream>>>(x, y, Xall);
  if (fresh) {
    // re-arm sentinels every call (graph replays leave old h values behind)
    (void)hipMemsetAsync(Hh, 0xFF, (size_t)(T_ + 1) * 4 * 16384 * 2, stream);
  } else {
    (void)hipMemsetAsync(flags, 0, 4096, stream);
    (void)hipMemsetAsync(Hh, 0, (size_t)2 * 4 * 16384 * 2, stream);
  }

  if (fresh)
    lstm_persist<true><<<NB_, 256, 0, stream>>>(Xall, Bp, bf, bi, bu, bo, Hh, out, flags);
  else
    lstm_persist<false><<<NB_, 256, 0, stream>>>(Xall, Bp, bf, bi, bu, bo, Hh, out, flags);
}

// Round 18
// 666.631 us; speedup vs baseline: 1.2275x; 1.2275x over previous
//
#include <hip/hip_runtime.h>
#include <hip/hip_bf16.h>

#define B_ 64
#define T_ 256
#define H_ 1024
#define NB_ 256  // 4 groups x 64 col-blocks

typedef __attribute__((ext_vector_type(8))) short short8;
typedef __attribute__((ext_vector_type(4))) float float4_;
typedef unsigned long long u64;

static __device__ __forceinline__ ushort f2bf(float v) {
  __hip_bfloat16 b = __float2bfloat16(v);
  return *reinterpret_cast<ushort*>(&b);
}
static __device__ __forceinline__ float bf2f(ushort u) {
  unsigned int x = ((unsigned int)u) << 16;
  return __builtin_bit_cast(float, x);
}
static __device__ __forceinline__ float sigm(float v) { return 1.0f / (1.0f + __expf(-v)); }
static __device__ __forceinline__ float tanh_fast(float v) {
  float e = __expf(2.0f * v);
  return 1.0f - 2.0f / (e + 1.0f);
}
// sentinel = 0xFFFF (bf16 -NaN). |h| < 1 -> data bf16 never sets bit14;
// the sentinel always does. One AND+compare tests the OR of all words.
static __device__ __forceinline__ bool anyS(u64 q) {
  return (q & 0x4000400040004000ull) != 0ull;
}

// Xall[t][b][j] bf16: j even = x[b][j/2][t], j odd = y[b][j/2][t-1] (0 at t=0)
__global__ __launch_bounds__(256) void build_X(const float* __restrict__ x,
                                               const float* __restrict__ y,
                                               ushort* __restrict__ Xall) {
  __shared__ float xl[128][33];
  __shared__ float yl[128][33];
  int b = blockIdx.x >> 3;
  int t0 = (blockIdx.x & 7) * 32;
  int tid = threadIdx.x;
  for (int it = 0; it < 16; ++it) {
    int idx = it * 256 + tid;
    int s = idx >> 5, tt = idx & 31;
    xl[s][tt] = x[((size_t)b * 128 + s) * T_ + t0 + tt];
    int ty = t0 + tt - 1;
    yl[s][tt] = (ty >= 0) ? y[((size_t)b * 128 + s) * T_ + ty] : 0.0f;
  }
  __syncthreads();
  for (int tt = 0; tt < 32; ++tt) {
    float v = (tid & 1) ? yl[tid >> 1][tt] : xl[tid >> 1][tt];
    Xall[((size_t)(t0 + tt) * B_ + b) * 256 + tid] = f2bf(v);
  }
}

// Bp[(((cbl*8 + w)*20 + u)*64 + l)*8 + j]
// wave w = ct*2 + kq; frag u: kk = (u<4)? 4kq+u : 8+16kq+(u-4)
// lane l: B[k = 32kk + 8*(l>>4) + j][col_in_gate = cbl*16 + (l&15)], gate ct
__global__ __launch_bounds__(256) void prep_weights(const float* __restrict__ Wf,
                                                    const float* __restrict__ Wi,
                                                    const float* __restrict__ Wu,
                                                    const float* __restrict__ Wo,
                                                    ushort* __restrict__ Bp) {
  int flat = blockIdx.x * 256 + threadIdx.x;
  int l = flat & 63;
  int r = flat >> 6;
  int u = r % 20;
  int r2 = r / 20;          // cbl*8 + w
  int w = r2 & 7;
  int cbl = r2 >> 3;        // 0..63
  int ct = w >> 1, kq = w & 1;
  int kk = (u < 4) ? (4 * kq + u) : (8 + 16 * kq + (u - 4));
  const float* W = (ct == 0) ? Wf : (ct == 1) ? Wi : (ct == 2) ? Wu : Wo;
  int col = cbl * 16 + (l & 15);
  ushort tmp[8];
#pragma unroll
  for (int j = 0; j < 8; ++j) {
    int k = kk * 32 + (l >> 4) * 8 + j;
    tmp[j] = f2bf(W[(size_t)k * H_ + col]);
  }
  *(short8*)(Bp + (size_t)flat * 8) = *(short8*)tmp;
}

// Persistent LSTM, batch-split 4 groups x 64 col-blocks (grid 256).
// ROUND-16 STRUCTURE (512 threads, 8 waves, K-split 2, sentinel protocol).
// Single change: OVERLAPPED double-buffered sentinel polling — a younger
// probe set is always in flight while the older set is checked, halving
// the detection granularity vs the serial issue->wait->check loop.
template <bool FRESH>
__global__ __launch_bounds__(512) void lstm_persist(
    const ushort* __restrict__ Xall, const ushort* __restrict__ Bp,
    const float* __restrict__ bfp, const float* __restrict__ bip,
    const float* __restrict__ bup, const float* __restrict__ bop,
    ushort* __restrict__ Hh, float* __restrict__ out,
    unsigned int* __restrict__ flags) {
  __shared__ ushort stg[16][1056];     // 33 KB h(t) slice (64 B row pad)
  __shared__ float gbuf[4][2][16][17]; // 8.7 KB [ct][kq][row][col]
  __shared__ ushort hbuf[16][16][17];  // 8.7 KB out-burst (16 steps)
  const int tid = threadIdx.x;
  const int w = tid >> 6, l = tid & 63;
  const int ct = w >> 1, kq = w & 1;
  const int ar = l & 15, kg = l >> 4;
  const int g = blockIdx.x & 3, cbl = blockIdx.x >> 2;

  short8 bfrag[20];
  {
    const ushort* bp0 = Bp + (((size_t)(cbl * 8 + w) * 20) * 64 + l) * 8;
#pragma unroll
    for (int u = 0; u < 20; ++u) bfrag[u] = *(const short8*)(bp0 + (size_t)u * 512);
  }
#pragma unroll
  for (int u = 0; u < 20; ++u) asm volatile("" : "+v"(bfrag[u]));

  const int b_ep = tid >> 4, hc16 = tid & 15;  // epilogue ids (tid<256)
  float biasF = 0, biasI = 0, biasU = 0, biasO = 0, creg = 0;
  if (tid < 256) {
    int c = cbl * 16 + hc16;
    biasF = bfp[c]; biasI = bip[c]; biasU = bup[c]; biasO = bop[c];
  }

#define AL(p) __hip_atomic_load((p), __ATOMIC_RELAXED, __HIP_MEMORY_SCOPE_AGENT)

  for (int t = 0; t < T_; ++t) {
    // ---- x-part: 4 MFMAs (kk = 4kq..4kq+3) ----
    const ushort* xrow = Xall + ((size_t)t * B_ + 16 * g + ar) * 256 + kg * 8;
    float4_ a0 = {0.f, 0.f, 0.f, 0.f}, a1 = {0.f, 0.f, 0.f, 0.f};
#pragma unroll
    for (int u = 0; u < 4; ++u) {
      short8 av = *(const short8*)(xrow + (4 * kq + u) * 32);
      if (u & 1) a1 = __builtin_amdgcn_mfma_f32_16x16x32_bf16(av, bfrag[u], a1, 0, 0, 0);
      else       a0 = __builtin_amdgcn_mfma_f32_16x16x32_bf16(av, bfrag[u], a0, 0, 0, 0);
    }
    if (t > 0) {
      if (!FRESH) {  // flag protocol fallback
        if (tid < 64) {
          unsigned int tgt = (unsigned int)t;
          while (true) {
            unsigned int f0 = __hip_atomic_load(&flags[g * 64 + l], __ATOMIC_RELAXED,
                                                __HIP_MEMORY_SCOPE_AGENT);
            if (__all(f0 >= tgt)) break;
            __builtin_amdgcn_s_sleep(1);
          }
          asm volatile("" ::: "memory");
        }
        __syncthreads();
      }
      // ---- stage rows w and w+8 of h(t): 64 B/lane total ----
      {
        const ushort* slot = Hh + ((size_t)(FRESH ? t : (t & 1)) * 4 + g) * 16384;
        const u64* pA = (const u64*)(slot + (size_t)w * 1024);        // row w
        const u64* pB = (const u64*)(slot + (size_t)(w + 8) * 1024);  // row w+8
        u64 q0, q1, q2, q3, q4, q5, q6, q7;
        if (FRESH) {
          q0 = pA[2 * l];       q1 = pA[2 * l + 1];      // plain first attempt
          q2 = pA[128 + 2 * l]; q3 = pA[129 + 2 * l];
          q4 = pB[2 * l];       q5 = pB[2 * l + 1];
          q6 = pB[128 + 2 * l]; q7 = pB[129 + 2 * l];
          if (anyS(q0 | q1 | q2 | q3 | q4 | q5 | q6 | q7)) {
            // overlapped agent polling: set r issued, then loop issuing the
            // alternate set BEFORE checking the in-flight one.
            u64 r0 = AL(pA + 2 * l),       r1 = AL(pA + 2 * l + 1);
            u64 r2 = AL(pA + 128 + 2 * l), r3 = AL(pA + 129 + 2 * l);
            u64 r4 = AL(pB + 2 * l),       r5 = AL(pB + 2 * l + 1);
            u64 r6 = AL(pB + 128 + 2 * l), r7 = AL(pB + 129 + 2 * l);
            for (;;) {
              // issue younger set into q (stays in flight during r-check)
              q0 = AL(pA + 2 * l);       q1 = AL(pA + 2 * l + 1);
              q2 = AL(pA + 128 + 2 * l); q3 = AL(pA + 129 + 2 * l);
              q4 = AL(pB + 2 * l);       q5 = AL(pB + 2 * l + 1);
              q6 = AL(pB + 128 + 2 * l); q7 = AL(pB + 129 + 2 * l);
              if (!anyS(r0 | r1 | r2 | r3 | r4 | r5 | r6 | r7)) {
                q0 = r0; q1 = r1; q2 = r2; q3 = r3;
                q4 = r4; q5 = r5; q6 = r6; q7 = r7;
                break;
              }
              // issue younger set into r, then check q
              r0 = AL(pA + 2 * l);       r1 = AL(pA + 2 * l + 1);
              r2 = AL(pA + 128 + 2 * l); r3 = AL(pA + 129 + 2 * l);
              r4 = AL(pB + 2 * l);       r5 = AL(pB + 2 * l + 1);
              r6 = AL(pB + 128 + 2 * l); r7 = AL(pB + 129 + 2 * l);
              if (!anyS(q0 | q1 | q2 | q3 | q4 | q5 | q6 | q7)) break;
              __builtin_amdgcn_s_sleep(1);
            }
          }
        } else {
          q0 = AL(pA + 2 * l);       q1 = AL(pA + 2 * l + 1);
          q2 = AL(pA + 128 + 2 * l); q3 = AL(pA + 129 + 2 * l);
          q4 = AL(pB + 2 * l);       q5 = AL(pB + 2 * l + 1);
          q6 = AL(pB + 128 + 2 * l); q7 = AL(pB + 129 + 2 * l);
        }
        union { u64 q[2]; short8 s; } c0, c1, c2, c3;
        c0.q[0] = q0; c0.q[1] = q1; c1.q[0] = q2; c1.q[1] = q3;
        c2.q[0] = q4; c2.q[1] = q5; c3.q[0] = q6; c3.q[1] = q7;
        *(short8*)&stg[w][l * 8] = c0.s;
        *(short8*)&stg[w][512 + l * 8] = c1.s;
        *(short8*)&stg[w + 8][l * 8] = c2.s;
        *(short8*)&stg[w + 8][512 + l * 8] = c3.s;
      }
      __syncthreads();
      // ---- h-part: 16 MFMAs from LDS (kk = 8+16kq .. 23+16kq) ----
#pragma unroll
      for (int u = 4; u < 20; ++u) {
        int kk = 8 + 16 * kq + (u - 4);
        short8 av = *(const short8*)&stg[ar][(kk - 8) * 32 + kg * 8];
        if (u & 1) a1 = __builtin_amdgcn_mfma_f32_16x16x32_bf16(av, bfrag[u], a1, 0, 0, 0);
        else       a0 = __builtin_amdgcn_mfma_f32_16x16x32_bf16(av, bfrag[u], a0, 0, 0, 0);
      }
    }
    float4_ acc = a0 + a1;
#pragma unroll
    for (int r = 0; r < 4; ++r) gbuf[ct][kq][kg * 4 + r][ar] = acc[r];
    __syncthreads();
    // ---- epilogue: 256 threads own one (b, hcol); publish fused ----
    if (tid < 256) {
      float f  = gbuf[0][0][b_ep][hc16] + gbuf[0][1][b_ep][hc16] + biasF;
      float i  = gbuf[1][0][b_ep][hc16] + gbuf[1][1][b_ep][hc16] + biasI;
      float uu = gbuf[2][0][b_ep][hc16] + gbuf[2][1][b_ep][hc16] + biasU;
      float o  = gbuf[3][0][b_ep][hc16] + gbuf[3][1][b_ep][hc16] + biasO;
      creg = fmaf(creg, sigm(f), sigm(i) * tanh_fast(uu));
      float h = sigm(o) * tanh_fast(creg);
      ushort hv = f2bf(h);
      // publish: pack 4 lanes' bf16 via in-wave shuffles; l%4==0 stores 8 B
      unsigned int hw = hv;
      unsigned int h1 = __shfl_down(hw, 1);
      unsigned int h2 = __shfl_down(hw, 2);
      unsigned int h3 = __shfl_down(hw, 3);
      if ((l & 3) == 0) {
        u64 q = (u64)hw | ((u64)h1 << 16) | ((u64)h2 << 32) | ((u64)h3 << 48);
        u64* dst = (u64*)(Hh +
            ((size_t)(FRESH ? (t + 1) : ((t + 1) & 1)) * 4 + g) * 16384 +
            (size_t)b_ep * 1024 + cbl * 16 + hc16);
        __hip_atomic_store(dst, q, __ATOMIC_RELAXED, __HIP_MEMORY_SCOPE_AGENT);
      }
      hbuf[b_ep][hc16][t & 15] = hv;
      if ((t & 15) == 15) {  // 64 B line-exact burst per thread
        float* orow = out + ((size_t)(16 * g + b_ep) * H_ + cbl * 16 + hc16) * T_ + (t - 15);
#pragma unroll
        for (int tt = 0; tt < 16; tt += 4) {
          float4 v = {bf2f(hbuf[b_ep][hc16][tt]), bf2f(hbuf[b_ep][hc16][tt + 1]),
                      bf2f(hbuf[b_ep][hc16][tt + 2]), bf2f(hbuf[b_ep][hc16][tt + 3])};
          *(float4*)(orow + tt) = v;
        }
      }
    }
    // herd-hold: nobody starts next-t sentinel spinning before publishes
    __syncthreads();
    if (!FRESH) {
      asm volatile("s_waitcnt vmcnt(0)" ::: "memory");
      __syncthreads();
      if (tid == 0)
        __hip_atomic_store(&flags[g * 64 + cbl], (unsigned int)(t + 1), __ATOMIC_RELAXED,
                           __HIP_MEMORY_SCOPE_AGENT);
    }
  }
#undef AL
  // ---- final c ----
  if (tid < 256)
    out[(size_t)B_ * H_ * T_ + (size_t)(16 * g + b_ep) * H_ + cbl * 16 + hc16] = creg;
}

extern "C" void kernel_launch(void* const* d_in, const int* in_sizes, int n_in,
                              void* d_out, int out_size, void* d_ws, size_t ws_size,
                              hipStream_t stream) {
  const float* x  = (const float*)d_in[0];
  const float* y  = (const float*)d_in[2];
  const float* Wf = (const float*)d_in[3];  const float* bf = (const float*)d_in[4];
  const float* Wi = (const float*)d_in[5];  const float* bi = (const float*)d_in[6];
  const float* Wu = (const float*)d_in[7];  const float* bu = (const float*)d_in[8];
  const float* Wo = (const float*)d_in[9];  const float* bo = (const float*)d_in[10];
  float* out = (float*)d_out;

  char* p = (char*)d_ws;
  ushort* Bp = (ushort*)p;        p += (size_t)64 * 8 * 20 * 64 * 8 * 2;   // 10.49 MB
  ushort* Xall = (ushort*)p;      p += (size_t)T_ * B_ * 256 * 2;          // 8.39 MB
  unsigned int* flags = (unsigned int*)p; p += 4096;
  ushort* Hh = (ushort*)p;        // FRESH: (T+1) x 4 x 32 KB = 33.6 MB
  size_t head = (size_t)(p - (char*)d_ws);
  bool fresh = ws_size >= head + (size_t)(T_ + 1) * 4 * 16384 * 2;

  prep_weights<<<(64 * 8 * 20 * 64) / 256, 256, 0, stream>>>(Wf, Wi, Wu, Wo, Bp);
  build_X<<<B_ * 8, 256, 0, stream>>>(x, y, Xall);
  if (fresh) {
    // re-arm sentinels every call (graph replays leave old h values behind)
    (void)hipMemsetAsync(Hh, 0xFF, (size_t)(T_ + 1) * 4 * 16384 * 2, stream);
  } else {
    (void)hipMemsetAsync(flags, 0, 4096, stream);
    (void)hipMemsetAsync(Hh, 0, (size_t)2 * 4 * 16384 * 2, stream);
  }

  if (fresh)
    lstm_persist<true><<<NB_, 512, 0, stream>>>(Xall, Bp, bf, bi, bu, bo, Hh, out, flags);
  else
    lstm_persist<false><<<NB_, 512, 0, stream>>>(Xall, Bp, bf, bi, bu, bo, Hh, out, flags);
}